// Round 14
// baseline (339.652 us; speedup 1.0000x reference)
//
#include <hip/hip_runtime.h>
#include <hip/hip_bf16.h>
#include <math.h>

#define C_CLASSES 100000
#define EMBED     384
#define BATCH     512
#define S_SCALE   64.0f
#define COS_M_    0.8775825618903728f
#define SIN_M_    0.479425538604203f
#define TH_       (-0.8775825618903728f)
#define MM_       0.2397127693021015f
#define EPS_      1e-7f
#define LOG2E_    1.4426950408889634f
#define LN2_      0.6931471805599453f
#define BIGZ_     92.33261191693459f      /* 64 * log2(e) */
#define SK1_      92.33248f               /* fp32(S * log2(e)) */

#define CT    64
#define NCH   1563                         // ceil(100000/64); last chunk padded
#define NB    256                          // persistent blocks

typedef __attribute__((ext_vector_type(8))) short bf16x8;
typedef __attribute__((ext_vector_type(4))) float f32x4;

__device__ inline ushort f2bf(float f) {
    unsigned u = __float_as_uint(f);
    unsigned r = (u + 0x7fffu + ((u >> 16) & 1u)) >> 16;   // RNE
    return (ushort)r;
}

// ---------------------------------------------------------------------------
// Kernel 0: convert E to bf16, packed in MFMA A-fragment order:
//   eP[((tile*12 + ks)*64 + lane)*8 + j] = bf16(E[tile*16 + (lane&15)]
//                                               [ks*32 + (lane>>4)*8 + j])
// ---------------------------------------------------------------------------
__global__ __launch_bounds__(256)
void cvt_pack_e(const float* __restrict__ emb, ushort* __restrict__ eP)
{
    int t = blockIdx.x * 256 + threadIdx.x;      // 0 .. 24575
    int lane = t & 63;
    int grp  = t >> 6;                           // tile*12 + ks
    int tile = grp / 12, ks = grp % 12;
    int lr = lane & 15, lg = lane >> 4;
    int row = tile * 16 + lr;
    int col = ks * 32 + lg * 8;
    const float4* src = (const float4*)(emb + (size_t)row * EMBED + col);
    float4 v0 = src[0], v1 = src[1];
    ushort4 o0, o1;
    o0.x = f2bf(v0.x); o0.y = f2bf(v0.y); o0.z = f2bf(v0.z); o0.w = f2bf(v0.w);
    o1.x = f2bf(v1.x); o1.y = f2bf(v1.y); o1.z = f2bf(v1.z); o1.w = f2bf(v1.w);
    ((ushort4*)eP)[t * 2]     = o0;
    ((ushort4*)eP)[t * 2 + 1] = o1;
}

// ---------------------------------------------------------------------------
// Kernel 1: persistent in-block chunk pipeline.
// 256 blocks x 1024 thr (16 waves, 1 block/CU, LDS 98 KB). Per chunk k:
//   top:  issue global loads of chunk k+1's W rows (wv0..wv5, in flight)
//   mid:  MFMA on Bl[k&1] (wave (mg,nh): 4 Mtiles x 2 Ntiles x 12 ks)
//         + fixed-max LSE epilogue with rare margin fixup
//   end:  butterfly sumsq(wv) -> scale -> bf16 -> swizzled pack Bl[(k+1)&1]
//   __syncthreads()  (vmcnt drain is free: loads had the whole phase)
// ---------------------------------------------------------------------------
__global__ __launch_bounds__(1024, 4)
void arc_pipe64(const ushort* __restrict__ eP, const int* __restrict__ labels,
                const float* __restrict__ weight,
                float* __restrict__ psum, float* __restrict__ zlabel)
{
    __shared__ ushort Bl[2][4 * 12 * 512];     // 2 x 49152 B
    __shared__ int    labL[BATCH];

    const int tid = threadIdx.x;
    const int blk = blockIdx.x;
    const int nch = 6 + ((blk < (NCH - 6 * NB)) ? 1 : 0);   // 27 blocks do 7

    if (tid < BATCH) labL[tid] = labels[tid];

    // pack role: 16 lanes per row, 64 rows
    const int c  = tid >> 4;           // row within chunk 0..63
    const int p  = tid & 15;
    const int t2 = c >> 4;             // tile 0..3
    const int cl = c & 15;

    // mfma role
    const int wid = tid >> 6, l = tid & 63;
    const int lr  = l & 15,  lg = l >> 4;
    const int mg  = wid & 7;           // row group: rows mg*64..+63
    const int nh  = wid >> 3;          // class half: cls nh*32..+31

    const ushort* abase = eP + ((size_t)(mg * 4) * 12 * 64 + l) * 8;

    float4 wv0, wv1, wv2, wv3, wv4, wv5;

#define LOADW(CH) do {                                                        \
        int row_ = (CH) * CT + c;                                             \
        if (row_ >= C_CLASSES) row_ = C_CLASSES - 1;                          \
        const float4* s_ = (const float4*)(weight + (size_t)row_ * EMBED) + p;\
        wv0 = s_[0];  wv1 = s_[16]; wv2 = s_[32];                             \
        wv3 = s_[48]; wv4 = s_[64]; wv5 = s_[80];                             \
    } while (0)

#define PACK1(W, I, BUF) do {                                                 \
        int q_   = p + 16 * (I);                                              \
        int ks_  = q_ >> 3;                                                   \
        int lgp_ = (q_ >> 1) & 3;                                             \
        int by_  = (((t2 * 12 + ks_) * 64) + cl + 16 * lgp_) * 16             \
                 + (q_ & 1) * 8;                                              \
        by_ ^= (((t2 * 12 + ks_) + lgp_) & 7) << 4;                           \
        ushort4 o_;                                                           \
        o_.x = f2bf((W).x * inv_); o_.y = f2bf((W).y * inv_);                 \
        o_.z = f2bf((W).z * inv_); o_.w = f2bf((W).w * inv_);                 \
        *(ushort4*)((char*)&Bl[BUF][0] + by_) = o_;                           \
    } while (0)

#define PACKW(BUF) do {                                                       \
        float ss_ = wv0.x*wv0.x + wv0.y*wv0.y + wv0.z*wv0.z + wv0.w*wv0.w     \
                  + wv1.x*wv1.x + wv1.y*wv1.y + wv1.z*wv1.z + wv1.w*wv1.w     \
                  + wv2.x*wv2.x + wv2.y*wv2.y + wv2.z*wv2.z + wv2.w*wv2.w     \
                  + wv3.x*wv3.x + wv3.y*wv3.y + wv3.z*wv3.z + wv3.w*wv3.w     \
                  + wv4.x*wv4.x + wv4.y*wv4.y + wv4.z*wv4.z + wv4.w*wv4.w     \
                  + wv5.x*wv5.x + wv5.y*wv5.y + wv5.z*wv5.z + wv5.w*wv5.w;    \
        ss_ += __shfl_xor(ss_, 1, 64); ss_ += __shfl_xor(ss_, 2, 64);         \
        ss_ += __shfl_xor(ss_, 4, 64); ss_ += __shfl_xor(ss_, 8, 64);         \
        const float inv_ = (ss_ > 0.f) ? rsqrtf(ss_) : 0.f;                   \
        PACK1(wv0, 0, BUF); PACK1(wv1, 1, BUF); PACK1(wv2, 2, BUF);           \
        PACK1(wv3, 3, BUF); PACK1(wv4, 4, BUF); PACK1(wv5, 5, BUF);           \
    } while (0)

    // ---- prologue: chunk 0 -> Bl[0] ----
    LOADW(blk);
    PACKW(0);
    __syncthreads();

    int ch = blk;
    for (int k = 0; k < nch; ++k) {
        // ---- issue next chunk's loads (in flight through the compute) ----
        if (k + 1 < nch) LOADW(ch + NB);

        const int c0    = ch * CT;
        const int cur   = k & 1;
        const bool tail = (ch == NCH - 1);

        // ---- MFMA: 4 Mtiles x 2 Ntiles x 12 ks ----
        f32x4 acc[4][2];
        #pragma unroll
        for (int mt = 0; mt < 4; ++mt) {
            acc[mt][0] = (f32x4){0.f, 0.f, 0.f, 0.f};
            acc[mt][1] = (f32x4){0.f, 0.f, 0.f, 0.f};
        }

        #pragma unroll
        for (int ks = 0; ks < 12; ++ks) {
            bf16x8 a0 = *(const bf16x8*)(abase + (0 * 12 + ks) * 512);
            bf16x8 a1 = *(const bf16x8*)(abase + (1 * 12 + ks) * 512);
            bf16x8 a2 = *(const bf16x8*)(abase + (2 * 12 + ks) * 512);
            bf16x8 a3 = *(const bf16x8*)(abase + (3 * 12 + ks) * 512);
            const int tt0 = nh * 2,     g0 = (tt0 * 12 + ks);
            const int tt1 = nh * 2 + 1, g1 = (tt1 * 12 + ks);
            int by0 = (g0 * 64 + l) * 16;  by0 ^= ((g0 + lg) & 7) << 4;
            int by1 = (g1 * 64 + l) * 16;  by1 ^= ((g1 + lg) & 7) << 4;
            bf16x8 b0 = *(const bf16x8*)((const char*)&Bl[cur][0] + by0);
            bf16x8 b1 = *(const bf16x8*)((const char*)&Bl[cur][0] + by1);
            acc[0][0] = __builtin_amdgcn_mfma_f32_16x16x32_bf16(a0, b0, acc[0][0], 0, 0, 0);
            acc[1][0] = __builtin_amdgcn_mfma_f32_16x16x32_bf16(a1, b0, acc[1][0], 0, 0, 0);
            acc[2][0] = __builtin_amdgcn_mfma_f32_16x16x32_bf16(a2, b0, acc[2][0], 0, 0, 0);
            acc[3][0] = __builtin_amdgcn_mfma_f32_16x16x32_bf16(a3, b0, acc[3][0], 0, 0, 0);
            acc[0][1] = __builtin_amdgcn_mfma_f32_16x16x32_bf16(a0, b1, acc[0][1], 0, 0, 0);
            acc[1][1] = __builtin_amdgcn_mfma_f32_16x16x32_bf16(a1, b1, acc[1][1], 0, 0, 0);
            acc[2][1] = __builtin_amdgcn_mfma_f32_16x16x32_bf16(a2, b1, acc[2][1], 0, 0, 0);
            acc[3][1] = __builtin_amdgcn_mfma_f32_16x16x32_bf16(a3, b1, acc[3][1], 0, 0, 0);
        }

        // ---- epilogue: fixed-max LSE + rare margin fixup ----
        const int cbase = c0 + nh * 32;
        #pragma unroll
        for (int mt = 0; mt < 4; ++mt) {
            #pragma unroll
            for (int rg = 0; rg < 4; ++rg) {
                const int r   = mg * 64 + mt * 16 + lg * 4 + rg;
                const int lab = labL[r];
                float acc4 = 0.f;
                if (!tail) {
                    #pragma unroll
                    for (int nt = 0; nt < 2; ++nt) {
                        float cv = acc[mt][nt][rg];
                        cv = fminf(fmaxf(cv, -1.f + EPS_), 1.f - EPS_);
                        acc4 += exp2f(fmaf(cv, SK1_, -BIGZ_));
                    }
                } else {
                    #pragma unroll
                    for (int nt = 0; nt < 2; ++nt) {
                        float cv = acc[mt][nt][rg];
                        cv = fminf(fmaxf(cv, -1.f + EPS_), 1.f - EPS_);
                        float z = fmaf(cv, SK1_, -BIGZ_);
                        int gc = cbase + nt * 16 + lr;
                        if (gc >= C_CLASSES) z = -1e30f;
                        acc4 += exp2f(z);
                    }
                }
                int off = lab - cbase;
                if (((unsigned)off < 32u) && ((off & 15) == lr)) {
                    float cv = (off >> 4) ? acc[mt][1][rg] : acc[mt][0][rg];
                    cv = fminf(fmaxf(cv, -1.f + EPS_), 1.f - EPS_);
                    float plain = exp2f(fmaf(cv, SK1_, -BIGZ_));
                    float zm;
                    if (cv > TH_) {
                        float sv = sqrtf(fmaxf(1.f - cv * cv, 0.f));
                        zm = S_SCALE * (cv * COS_M_ - sv * SIN_M_);
                    } else {
                        zm = S_SCALE * (cv - MM_);
                    }
                    acc4 += exp2f(fmaf(zm, LOG2E_, -BIGZ_)) - plain;
                    zlabel[r] = zm;
                }
                acc4 += __shfl_xor(acc4, 1, 64);
                acc4 += __shfl_xor(acc4, 2, 64);
                acc4 += __shfl_xor(acc4, 4, 64);
                acc4 += __shfl_xor(acc4, 8, 64);
                if (lr == 0)
                    psum[((size_t)ch * 2 + nh) * BATCH + r] = acc4;
            }
        }

        // ---- pack next chunk into the other buffer, one barrier ----
        if (k + 1 < nch) PACKW((k + 1) & 1);
        __syncthreads();
        ch += NB;
    }
#undef LOADW
#undef PACK1
#undef PACKW
}

// ---------------------------------------------------------------------------
// Kernel 2: sum 2*NCH chunk-half partials per row -> row loss
// ---------------------------------------------------------------------------
__global__ __launch_bounds__(256)
void arc_reduce(const float* __restrict__ psum, const float* __restrict__ zlabel,
                float* __restrict__ rowloss)
{
    const int r = blockIdx.x;
    const int tid = threadIdx.x;
    float s = 0.f;
    for (int k = tid; k < 2 * NCH; k += 256)
        s += psum[(size_t)k * BATCH + r];
    #pragma unroll
    for (int d = 1; d < 64; d <<= 1) s += __shfl_xor(s, d, 64);
    __shared__ float ssh[4];
    if ((tid & 63) == 0) ssh[tid >> 6] = s;
    __syncthreads();
    if (tid == 0) {
        float t = ssh[0] + ssh[1] + ssh[2] + ssh[3];
        rowloss[r] = LN2_ * (BIGZ_ + log2f(t)) - zlabel[r];
    }
}

// ---------------------------------------------------------------------------
// Kernel 3: mean over rows
// ---------------------------------------------------------------------------
__global__ __launch_bounds__(512)
void arc_mean(const float* __restrict__ rowloss, float* __restrict__ out)
{
    const int tid = threadIdx.x;
    float v = rowloss[tid];
    #pragma unroll
    for (int d = 1; d < 64; d <<= 1) v += __shfl_xor(v, d, 64);
    __shared__ float sv[8];
    if ((tid & 63) == 0) sv[tid >> 6] = v;
    __syncthreads();
    if (tid == 0) {
        float t = 0.f;
        #pragma unroll
        for (int w = 0; w < 8; ++w) t += sv[w];
        out[0] = t / (float)BATCH;
    }
}

extern "C" void kernel_launch(void* const* d_in, const int* in_sizes, int n_in,
                              void* d_out, int out_size, void* d_ws, size_t ws_size,
                              hipStream_t stream)
{
    (void)in_sizes; (void)n_in; (void)out_size; (void)ws_size;
    const float* emb    = (const float*)d_in[0];
    const int*   labels = (const int*)d_in[1];
    const float* weight = (const float*)d_in[2];
    float* out = (float*)d_out;

    float*  psum    = (float*)d_ws;                      // [2*NCH][BATCH] 6.4MB
    float*  zlabel  = psum + (size_t)2 * NCH * BATCH;    // [BATCH]
    float*  rowloss = zlabel + BATCH;                    // [BATCH]
    ushort* eP      = (ushort*)(rowloss + BATCH);        // packed bf16 E frags

    cvt_pack_e<<<(BATCH * EMBED / 8) / 256, 256, 0, stream>>>(emb, eP);
    arc_pipe64<<<NB, 1024, 0, stream>>>(eP, labels, weight, psum, zlabel);
    arc_reduce<<<BATCH, 256, 0, stream>>>(psum, zlabel, rowloss);
    arc_mean<<<1, 512, 0, stream>>>(rowloss, out);
}

// Round 15
// 185.953 us; speedup vs baseline: 1.8266x; 1.8266x over previous
//
#include <hip/hip_runtime.h>
#include <hip/hip_bf16.h>
#include <math.h>

#define C_CLASSES 100000
#define EMBED     384
#define BATCH     512
#define S_SCALE   64.0f
#define COS_M_    0.8775825618903728f
#define SIN_M_    0.479425538604203f
#define TH_       (-0.8775825618903728f)
#define MM_       0.2397127693021015f
#define EPS_      1e-7f
#define LOG2E_    1.4426950408889634f
#define LN2_      0.6931471805599453f
#define BIGZ_     92.33261191693459f      /* 64 * log2(e) */
#define SK1_      92.33248f               /* fp32(S * log2(e)) */

#define CT    64
#define NCH   1563                         // ceil(100000/64); last chunk padded
#define NB    256                          // persistent blocks

typedef __attribute__((ext_vector_type(8))) short bf16x8;
typedef __attribute__((ext_vector_type(4))) float f32x4;

__device__ inline ushort f2bf(float f) {
    unsigned u = __float_as_uint(f);
    unsigned r = (u + 0x7fffu + ((u >> 16) & 1u)) >> 16;   // RNE
    return (ushort)r;
}

// ---------------------------------------------------------------------------
// Kernel 0: convert E to bf16, packed in MFMA A-fragment order:
//   eP[((tile*12 + ks)*64 + lane)*8 + j] = bf16(E[tile*16 + (lane&15)]
//                                               [ks*32 + (lane>>4)*8 + j])
// ---------------------------------------------------------------------------
__global__ __launch_bounds__(256)
void cvt_pack_e(const float* __restrict__ emb, ushort* __restrict__ eP)
{
    int t = blockIdx.x * 256 + threadIdx.x;      // 0 .. 24575
    int lane = t & 63;
    int grp  = t >> 6;                           // tile*12 + ks
    int tile = grp / 12, ks = grp % 12;
    int lr = lane & 15, lg = lane >> 4;
    int row = tile * 16 + lr;
    int col = ks * 32 + lg * 8;
    const float4* src = (const float4*)(emb + (size_t)row * EMBED + col);
    float4 v0 = src[0], v1 = src[1];
    ushort4 o0, o1;
    o0.x = f2bf(v0.x); o0.y = f2bf(v0.y); o0.z = f2bf(v0.z); o0.w = f2bf(v0.w);
    o1.x = f2bf(v1.x); o1.y = f2bf(v1.y); o1.z = f2bf(v1.z); o1.w = f2bf(v1.w);
    ((ushort4*)eP)[t * 2]     = o0;
    ((ushort4*)eP)[t * 2 + 1] = o1;
}

// ---------------------------------------------------------------------------
// Kernel 1: producer/consumer persistent kernel.
// grid = 256 x 768 (12 waves, 1 block/CU, LDS 98 KB).
//   waves 0-3  (256 thr): PRODUCER — load W rows of chunk k+1 global->reg
//               (two 32-row halves, 8 lanes/row), sumsq butterfly, scale,
//               bf16-pack into Bl[(k+1)&1]. Keeps HBM requests in flight
//               continuously.
//   waves 4-11 (512 thr): CONSUMER — r13's proven MFMA body on Bl[k&1]
//               (4Mt x 4Nt x 12ks, acc 64 AGPR) + fixed-max LSE epilogue.
// One __syncthreads per chunk (outside the role branch).
// ---------------------------------------------------------------------------
__global__ __launch_bounds__(768, 3)
void arc_pc(const ushort* __restrict__ eP, const int* __restrict__ labels,
            const float* __restrict__ weight,
            float* __restrict__ psum, float* __restrict__ zlabel)
{
    __shared__ ushort Bl[2][(CT / 16) * 12 * 512];   // 2 x 49152 B
    __shared__ int    labL[BATCH];

    const int tid = threadIdx.x;
    const int blk = blockIdx.x;
    const int nch = 6 + ((blk < (NCH - 6 * NB)) ? 1 : 0);   // 27 blocks do 7

    if (tid < BATCH) labL[tid] = labels[tid];

    const int wid = tid >> 6;
    const bool producer = (wid < 4);

    // ---------------- producer lambda-free macro ----------------
    // 256 threads, 8 lanes/row, two halves of 32 rows each.
#define STAGE(CH, BUF) do {                                                   \
        const int p_ = tid & 7;                                               \
        _Pragma("unroll")                                                     \
        for (int h_ = 0; h_ < 2; ++h_) {                                      \
            const int c_ = h_ * 32 + (tid >> 3);       /* 0..63 */            \
            int row_ = (CH) * CT + c_;                                        \
            if (row_ >= C_CLASSES) row_ = C_CLASSES - 1;                      \
            const float4* s_ =                                                \
                (const float4*)(weight + (size_t)row_ * EMBED) + p_;          \
            float4 wv_[12];                                                   \
            float ss_ = 0.f;                                                  \
            _Pragma("unroll")                                                 \
            for (int i_ = 0; i_ < 12; ++i_) {                                 \
                wv_[i_] = s_[8 * i_];                                         \
                ss_ += wv_[i_].x * wv_[i_].x + wv_[i_].y * wv_[i_].y          \
                     + wv_[i_].z * wv_[i_].z + wv_[i_].w * wv_[i_].w;         \
            }                                                                 \
            ss_ += __shfl_xor(ss_, 1, 64);                                    \
            ss_ += __shfl_xor(ss_, 2, 64);                                    \
            ss_ += __shfl_xor(ss_, 4, 64);                                    \
            const float inv_ = (ss_ > 0.f) ? rsqrtf(ss_) : 0.f;               \
            const int t2_ = c_ >> 4, cl_ = c_ & 15;                           \
            _Pragma("unroll")                                                 \
            for (int i_ = 0; i_ < 12; ++i_) {                                 \
                int q_   = p_ + 8 * i_;                                       \
                int ks_  = q_ >> 3;                                           \
                int lgp_ = (q_ >> 1) & 3;                                     \
                int jo_  = (q_ & 1) * 4;                                      \
                ushort4 o_;                                                   \
                o_.x = f2bf(wv_[i_].x * inv_); o_.y = f2bf(wv_[i_].y * inv_); \
                o_.z = f2bf(wv_[i_].z * inv_); o_.w = f2bf(wv_[i_].w * inv_); \
                *(ushort4*)&Bl[BUF][(size_t)(((t2_ * 12 + ks_) * 64)          \
                        + cl_ + 16 * lgp_) * 8 + jo_] = o_;                   \
            }                                                                 \
        }                                                                     \
    } while (0)

    // consumer geometry
    const int cw = wid - 4;                 // 0..7 (consumer wave)
    const int l  = tid & 63;
    const int lr = l & 15, lg = l >> 4;
    const ushort* abase = eP + ((size_t)(cw * 4) * 12 * 64 + l) * 8;

    // ---- prologue: producers stage chunk blk -> Bl[0] ----
    if (producer) STAGE(blk, 0);
    __syncthreads();

    int ch = blk;
    for (int k = 0; k < nch; ++k) {
        const int cur = k & 1;
        if (producer) {
            if (k + 1 < nch) STAGE(ch + NB, cur ^ 1);
        } else {
            const int  c0   = ch * CT;
            const bool tail = (ch == NCH - 1);

            f32x4 acc[4][4];
            #pragma unroll
            for (int mt = 0; mt < 4; ++mt)
                #pragma unroll
                for (int nt = 0; nt < 4; ++nt)
                    acc[mt][nt] = (f32x4){0.f, 0.f, 0.f, 0.f};

            #pragma unroll
            for (int ks = 0; ks < 12; ++ks) {
                bf16x8 a[4], b[4];
                #pragma unroll
                for (int mt = 0; mt < 4; ++mt)
                    a[mt] = *(const bf16x8*)(abase + (mt * 12 + ks) * 512);
                #pragma unroll
                for (int nt = 0; nt < 4; ++nt)
                    b[nt] = *(const bf16x8*)&Bl[cur][(size_t)((nt * 12 + ks) * 64 + l) * 8];
                #pragma unroll
                for (int mt = 0; mt < 4; ++mt)
                    #pragma unroll
                    for (int nt = 0; nt < 4; ++nt)
                        acc[mt][nt] = __builtin_amdgcn_mfma_f32_16x16x32_bf16(
                            a[mt], b[nt], acc[mt][nt], 0, 0, 0);
            }

            #pragma unroll
            for (int mt = 0; mt < 4; ++mt) {
                #pragma unroll
                for (int rg = 0; rg < 4; ++rg) {
                    const int r   = cw * 64 + mt * 16 + lg * 4 + rg;
                    const int lab = labL[r];
                    float acc4 = 0.f;
                    if (!tail) {
                        #pragma unroll
                        for (int nt = 0; nt < 4; ++nt) {
                            float cv = acc[mt][nt][rg];
                            cv = fminf(fmaxf(cv, -1.f + EPS_), 1.f - EPS_);
                            acc4 += exp2f(fmaf(cv, SK1_, -BIGZ_));
                        }
                    } else {
                        #pragma unroll
                        for (int nt = 0; nt < 4; ++nt) {
                            float cv = acc[mt][nt][rg];
                            cv = fminf(fmaxf(cv, -1.f + EPS_), 1.f - EPS_);
                            float z = fmaf(cv, SK1_, -BIGZ_);
                            int gc = c0 + nt * 16 + lr;
                            if (gc >= C_CLASSES) z = -1e30f;
                            acc4 += exp2f(z);
                        }
                    }
                    int off = lab - c0;
                    if (((unsigned)off < 64u) && ((off & 15) == lr)) {
                        int ntl = off >> 4;
                        float cv = (ntl == 0) ? acc[mt][0][rg]
                                 : (ntl == 1) ? acc[mt][1][rg]
                                 : (ntl == 2) ? acc[mt][2][rg]
                                              : acc[mt][3][rg];
                        cv = fminf(fmaxf(cv, -1.f + EPS_), 1.f - EPS_);
                        float plain = exp2f(fmaf(cv, SK1_, -BIGZ_));
                        float zm;
                        if (cv > TH_) {
                            float sv = sqrtf(fmaxf(1.f - cv * cv, 0.f));
                            zm = S_SCALE * (cv * COS_M_ - sv * SIN_M_);
                        } else {
                            zm = S_SCALE * (cv - MM_);
                        }
                        acc4 += exp2f(fmaf(zm, LOG2E_, -BIGZ_)) - plain;
                        zlabel[r] = zm;
                    }
                    acc4 += __shfl_xor(acc4, 1, 64);
                    acc4 += __shfl_xor(acc4, 2, 64);
                    acc4 += __shfl_xor(acc4, 4, 64);
                    acc4 += __shfl_xor(acc4, 8, 64);
                    if (lr == 0) psum[(size_t)ch * BATCH + r] = acc4;
                }
            }
        }
        __syncthreads();
        ch += NB;
    }
#undef STAGE
}

// ---------------------------------------------------------------------------
// Kernel 2: sum 1563 chunk-partials per row -> row loss
// ---------------------------------------------------------------------------
__global__ __launch_bounds__(256)
void arc_reduce(const float* __restrict__ psum, const float* __restrict__ zlabel,
                float* __restrict__ rowloss)
{
    const int r = blockIdx.x;
    const int tid = threadIdx.x;
    float s = 0.f;
    for (int k = tid; k < NCH; k += 256)
        s += psum[(size_t)k * BATCH + r];
    #pragma unroll
    for (int d = 1; d < 64; d <<= 1) s += __shfl_xor(s, d, 64);
    __shared__ float ssh[4];
    if ((tid & 63) == 0) ssh[tid >> 6] = s;
    __syncthreads();
    if (tid == 0) {
        float t = ssh[0] + ssh[1] + ssh[2] + ssh[3];
        rowloss[r] = LN2_ * (BIGZ_ + log2f(t)) - zlabel[r];
    }
}

// ---------------------------------------------------------------------------
// Kernel 3: mean over rows
// ---------------------------------------------------------------------------
__global__ __launch_bounds__(512)
void arc_mean(const float* __restrict__ rowloss, float* __restrict__ out)
{
    const int tid = threadIdx.x;
    float v = rowloss[tid];
    #pragma unroll
    for (int d = 1; d < 64; d <<= 1) v += __shfl_xor(v, d, 64);
    __shared__ float sv[8];
    if ((tid & 63) == 0) sv[tid >> 6] = v;
    __syncthreads();
    if (tid == 0) {
        float t = 0.f;
        #pragma unroll
        for (int w = 0; w < 8; ++w) t += sv[w];
        out[0] = t / (float)BATCH;
    }
}

extern "C" void kernel_launch(void* const* d_in, const int* in_sizes, int n_in,
                              void* d_out, int out_size, void* d_ws, size_t ws_size,
                              hipStream_t stream)
{
    (void)in_sizes; (void)n_in; (void)out_size; (void)ws_size;
    const float* emb    = (const float*)d_in[0];
    const int*   labels = (const int*)d_in[1];
    const float* weight = (const float*)d_in[2];
    float* out = (float*)d_out;

    float*  psum    = (float*)d_ws;                    // [NCH][BATCH]  3.2 MB
    float*  zlabel  = psum + (size_t)NCH * BATCH;      // [BATCH]
    float*  rowloss = zlabel + BATCH;                  // [BATCH]
    ushort* eP      = (ushort*)(rowloss + BATCH);      // packed bf16 E frags

    cvt_pack_e<<<(BATCH * EMBED / 8) / 256, 256, 0, stream>>>(emb, eP);
    arc_pc<<<NB, 768, 0, stream>>>(eP, labels, weight, psum, zlabel);
    arc_reduce<<<BATCH, 256, 0, stream>>>(psum, zlabel, rowloss);
    arc_mean<<<1, 512, 0, stream>>>(rowloss, out);
}

// Round 16
// 97.352 us; speedup vs baseline: 3.4889x; 1.9101x over previous
//
#include <hip/hip_runtime.h>
#include <hip/hip_bf16.h>
#include <math.h>

#define C_CLASSES 100000
#define EMBED     384
#define BATCH     512
#define S_SCALE   64.0f
#define COS_M_    0.8775825618903728f
#define SIN_M_    0.479425538604203f
#define TH_       (-0.8775825618903728f)
#define MM_       0.2397127693021015f
#define EPS_      1e-7f
#define LOG2E_    1.4426950408889634f
#define LN2_      0.6931471805599453f
#define BIGZ_     92.33261191693459f      /* 64 * log2(e) */
#define SK1_      92.33248f               /* fp32(S * log2(e)) */

#define CT    64
#define NCH   1563                         // ceil(100000/64); last chunk padded

typedef __attribute__((ext_vector_type(8))) short bf16x8;
typedef __attribute__((ext_vector_type(4))) float f32x4;

__device__ inline ushort f2bf(float f) {
    unsigned u = __float_as_uint(f);
    unsigned r = (u + 0x7fffu + ((u >> 16) & 1u)) >> 16;   // RNE
    return (ushort)r;
}

// ---------------------------------------------------------------------------
// Kernel 0: convert E to bf16, packed in MFMA A-fragment order:
//   eP[((tile*12 + ks)*64 + lane)*8 + j] = bf16(E[tile*16 + (lane&15)]
//                                               [ks*32 + (lane>>4)*8 + j])
// ---------------------------------------------------------------------------
__global__ __launch_bounds__(256)
void cvt_pack_e(const float* __restrict__ emb, ushort* __restrict__ eP)
{
    int t = blockIdx.x * 256 + threadIdx.x;      // 0 .. 24575
    int lane = t & 63;
    int grp  = t >> 6;                           // tile*12 + ks
    int tile = grp / 12, ks = grp % 12;
    int lr = lane & 15, lg = lane >> 4;
    int row = tile * 16 + lr;
    int col = ks * 32 + lg * 8;
    const float4* src = (const float4*)(emb + (size_t)row * EMBED + col);
    float4 v0 = src[0], v1 = src[1];
    ushort4 o0, o1;
    o0.x = f2bf(v0.x); o0.y = f2bf(v0.y); o0.z = f2bf(v0.z); o0.w = f2bf(v0.w);
    o1.x = f2bf(v1.x); o1.y = f2bf(v1.y); o1.z = f2bf(v1.z); o1.w = f2bf(v1.w);
    ((ushort4*)eP)[t * 2]     = o0;
    ((ushort4*)eP)[t * 2 + 1] = o1;
}

// ---------------------------------------------------------------------------
// Kernel 1: fused (r13 structure), spill-fenced + bank-swizzled pack.
//  phase 1: W global->reg in TWO half-passes (16 lanes/row, wv[6]=24 VGPR),
//           sched_barrier(0) between halves stops load-hoist spill;
//           pack writes XOR-swizzled (8-way -> 2-way).
//  phase 2: MFMA 8 waves x 4Mt x 4Nt x 12ks; A from L2-resident eP;
//           B reads use the matching XOR.
//  phase 3: fixed-max LSE + rare margin fixup; tail masking in last block.
// ---------------------------------------------------------------------------
__global__ __launch_bounds__(512, 4)
void arc_fused64(const ushort* __restrict__ eP, const int* __restrict__ labels,
                 const float* __restrict__ weight,
                 float* __restrict__ psum, float* __restrict__ zlabel)
{
    __shared__ ushort Bl[(CT / 16) * 12 * 512];    // 24576 ushorts = 49152 B
    __shared__ int    labL[BATCH];

    const int tid = threadIdx.x;

    // bijective XCD-aware swizzle (m204 form)
    const int orig = blockIdx.x;
    const int xcd  = orig & 7;
    const int qq   = NCH >> 3, rr = NCH & 7;       // 195, 3
    const int blk  = (xcd < rr ? xcd * (qq + 1)
                               : rr * (qq + 1) + (xcd - rr) * qq) + (orig >> 3);
    const int c0   = blk * CT;

    labL[tid] = labels[tid];

    // ---- phase 1: two half-passes of 32 rows each (16 lanes/row) ----
    {
        const int p = tid & 15;              // 16 lanes per class
        #pragma unroll
        for (int h = 0; h < 2; ++h) {
            const int c = h * 32 + (tid >> 4);       // class 0..63
            int row = c0 + c;
            if (row >= C_CLASSES) row = C_CLASSES - 1;   // pad rows: clamp
            const float4* src = (const float4*)(weight + (size_t)row * EMBED) + p;

            float4 wv[6];
            float ss = 0.f;
            #pragma unroll
            for (int i = 0; i < 6; ++i) {
                wv[i] = src[16 * i];
                ss += wv[i].x * wv[i].x + wv[i].y * wv[i].y
                    + wv[i].z * wv[i].z + wv[i].w * wv[i].w;
            }
            ss += __shfl_xor(ss, 1, 64);
            ss += __shfl_xor(ss, 2, 64);
            ss += __shfl_xor(ss, 4, 64);
            ss += __shfl_xor(ss, 8, 64);
            const float inv = (ss > 0.f) ? rsqrtf(ss) : 0.f;

            const int t2 = c >> 4, cl = c & 15;
            #pragma unroll
            for (int i = 0; i < 6; ++i) {
                int q   = p + 16 * i;        // quad index 0..95 (k = 4q..4q+3)
                int ks  = q >> 3;
                int lgp = (q >> 1) & 3;
                int jo  = (q & 1) * 4;
                ushort4 o;
                o.x = f2bf(wv[i].x * inv); o.y = f2bf(wv[i].y * inv);
                o.z = f2bf(wv[i].z * inv); o.w = f2bf(wv[i].w * inv);
                int ei = (int)(((t2 * 12 + ks) * 64) + cl + 16 * lgp) * 8 + jo;
                ei ^= (lgp & 3) << 4;                 // bank swizzle (write)
                *(ushort4*)&Bl[ei] = o;
            }
            // fence: stop half-1 loads hoisting over half-0 pack (spill fix)
            __builtin_amdgcn_sched_barrier(0);
        }
    }
    __syncthreads();     // packed B + labL ready

    // ---- phase 2: MFMA, 8 waves x (4 Mtiles x 4 Ntiles), K=384 ----
    const int wid = tid >> 6, l = tid & 63;
    const int lr  = l & 15,  lg = l >> 4;
    const int bxo = (lg & 3) << 4;                    // bank swizzle (read)

    const ushort* abase = eP + ((size_t)(wid * 4) * 12 * 64 + l) * 8;

    f32x4 acc[4][4];
    #pragma unroll
    for (int mt = 0; mt < 4; ++mt)
        #pragma unroll
        for (int nt = 0; nt < 4; ++nt)
            acc[mt][nt] = (f32x4){0.f, 0.f, 0.f, 0.f};

    #pragma unroll
    for (int ks = 0; ks < 12; ++ks) {
        bf16x8 a[4], b[4];
        #pragma unroll
        for (int mt = 0; mt < 4; ++mt)
            a[mt] = *(const bf16x8*)(abase + (mt * 12 + ks) * 512);
        #pragma unroll
        for (int nt = 0; nt < 4; ++nt) {
            int ei = (int)((nt * 12 + ks) * 64 + l) * 8;
            b[nt] = *(const bf16x8*)&Bl[ei ^ bxo];
        }
        #pragma unroll
        for (int mt = 0; mt < 4; ++mt)
            #pragma unroll
            for (int nt = 0; nt < 4; ++nt)
                acc[mt][nt] = __builtin_amdgcn_mfma_f32_16x16x32_bf16(
                    a[mt], b[nt], acc[mt][nt], 0, 0, 0);
    }

    // ---- phase 3: fixed-max LSE + rare margin fixup ----
    const bool tail = (blk == NCH - 1);
    #pragma unroll
    for (int mt = 0; mt < 4; ++mt) {
        #pragma unroll
        for (int rg = 0; rg < 4; ++rg) {
            const int r   = wid * 64 + mt * 16 + lg * 4 + rg;
            const int lab = labL[r];
            float acc4 = 0.f;
            if (!tail) {
                #pragma unroll
                for (int nt = 0; nt < 4; ++nt) {
                    float cv = acc[mt][nt][rg];
                    cv = fminf(fmaxf(cv, -1.f + EPS_), 1.f - EPS_);
                    acc4 += exp2f(fmaf(cv, SK1_, -BIGZ_));
                }
            } else {
                #pragma unroll
                for (int nt = 0; nt < 4; ++nt) {
                    float cv = acc[mt][nt][rg];
                    cv = fminf(fmaxf(cv, -1.f + EPS_), 1.f - EPS_);
                    float z = fmaf(cv, SK1_, -BIGZ_);
                    int gc = c0 + nt * 16 + lr;
                    if (gc >= C_CLASSES) z = -1e30f;
                    acc4 += exp2f(z);
                }
            }
            int off = lab - c0;
            if (((unsigned)off < 64u) && ((off & 15) == lr)) {
                int ntl = off >> 4;
                float cv = (ntl == 0) ? acc[mt][0][rg]
                         : (ntl == 1) ? acc[mt][1][rg]
                         : (ntl == 2) ? acc[mt][2][rg]
                                      : acc[mt][3][rg];
                cv = fminf(fmaxf(cv, -1.f + EPS_), 1.f - EPS_);
                float plain = exp2f(fmaf(cv, SK1_, -BIGZ_));
                float zm;
                if (cv > TH_) {
                    float sv = sqrtf(fmaxf(1.f - cv * cv, 0.f));
                    zm = S_SCALE * (cv * COS_M_ - sv * SIN_M_);
                } else {
                    zm = S_SCALE * (cv - MM_);
                }
                acc4 += exp2f(fmaf(zm, LOG2E_, -BIGZ_)) - plain;
                zlabel[r] = zm;
            }
            acc4 += __shfl_xor(acc4, 1, 64);
            acc4 += __shfl_xor(acc4, 2, 64);
            acc4 += __shfl_xor(acc4, 4, 64);
            acc4 += __shfl_xor(acc4, 8, 64);
            if (lr == 0) psum[(size_t)blk * BATCH + r] = acc4;
        }
    }
}

// ---------------------------------------------------------------------------
// Kernel 2: sum 1563 chunk-partials per row -> row loss
// ---------------------------------------------------------------------------
__global__ __launch_bounds__(256)
void arc_reduce(const float* __restrict__ psum, const float* __restrict__ zlabel,
                float* __restrict__ rowloss)
{
    const int r = blockIdx.x;
    const int tid = threadIdx.x;
    float s = 0.f;
    for (int k = tid; k < NCH; k += 256)
        s += psum[(size_t)k * BATCH + r];
    #pragma unroll
    for (int d = 1; d < 64; d <<= 1) s += __shfl_xor(s, d, 64);
    __shared__ float ssh[4];
    if ((tid & 63) == 0) ssh[tid >> 6] = s;
    __syncthreads();
    if (tid == 0) {
        float t = ssh[0] + ssh[1] + ssh[2] + ssh[3];
        rowloss[r] = LN2_ * (BIGZ_ + log2f(t)) - zlabel[r];
    }
}

// ---------------------------------------------------------------------------
// Kernel 3: mean over rows
// ---------------------------------------------------------------------------
__global__ __launch_bounds__(512)
void arc_mean(const float* __restrict__ rowloss, float* __restrict__ out)
{
    const int tid = threadIdx.x;
    float v = rowloss[tid];
    #pragma unroll
    for (int d = 1; d < 64; d <<= 1) v += __shfl_xor(v, d, 64);
    __shared__ float sv[8];
    if ((tid & 63) == 0) sv[tid >> 6] = v;
    __syncthreads();
    if (tid == 0) {
        float t = 0.f;
        #pragma unroll
        for (int w = 0; w < 8; ++w) t += sv[w];
        out[0] = t / (float)BATCH;
    }
}

extern "C" void kernel_launch(void* const* d_in, const int* in_sizes, int n_in,
                              void* d_out, int out_size, void* d_ws, size_t ws_size,
                              hipStream_t stream)
{
    (void)in_sizes; (void)n_in; (void)out_size; (void)ws_size;
    const float* emb    = (const float*)d_in[0];
    const int*   labels = (const int*)d_in[1];
    const float* weight = (const float*)d_in[2];
    float* out = (float*)d_out;

    float*  psum    = (float*)d_ws;                    // [NCH][BATCH]  3.2 MB
    float*  zlabel  = psum + (size_t)NCH * BATCH;      // [BATCH]
    float*  rowloss = zlabel + BATCH;                  // [BATCH]
    ushort* eP      = (ushort*)(rowloss + BATCH);      // packed bf16 E frags

    cvt_pack_e<<<(BATCH * EMBED / 8) / 256, 256, 0, stream>>>(emb, eP);
    arc_fused64<<<NCH, 512, 0, stream>>>(eP, labels, weight, psum, zlabel);
    arc_reduce<<<BATCH, 256, 0, stream>>>(psum, zlabel, rowloss);
    arc_mean<<<1, 512, 0, stream>>>(rowloss, out);
}